// Round 2
// baseline (777.484 us; speedup 1.0000x reference)
//
#include <hip/hip_runtime.h>
#include <math.h>

// Problem constants: B=128,N=8 -> M=1024 rows; D=768; T=512; V=49408
#define M_TOTAL 1024
#define DDIM    768
#define TDIM    512
#define VDIM    49408
#define CH      256          // V-chunk per fused-kernel iteration
#define NCH     193          // 49408 / 256
#define NSPLIT  32           // V splits (low bits of blockIdx -> XCD/L2 chunk sharing)
#define NQT     32           // 1024 / 32 query tiles

typedef __bf16 bf16;
typedef __bf16 bf16x8 __attribute__((ext_vector_type(8)));
typedef float  f32x4  __attribute__((ext_vector_type(4)));

// ---------------- Kernel A: kw = audio@W + b, row-normalize -> kwn (bf16) ----
__global__ __launch_bounds__(256) void k_proj(const float* __restrict__ audio,
        const float* __restrict__ W, const float* __restrict__ bias,
        bf16* __restrict__ kwn) {
    __shared__ float a_lds[8 * 768];
    __shared__ float kw_lds[8 * 512];
    __shared__ float rn_lds[8];
    const int tid = threadIdx.x;
    const int q0 = blockIdx.x * 8;

    const float4* asrc = (const float4*)(audio + q0 * 768);
    float4* adst = (float4*)a_lds;
    #pragma unroll
    for (int i = 0; i < 6; ++i) adst[i * 256 + tid] = asrc[i * 256 + tid];
    __syncthreads();

    float acc0[8], acc1[8];
    #pragma unroll
    for (int q = 0; q < 8; ++q) { acc0[q] = 0.f; acc1[q] = 0.f; }
    for (int d = 0; d < 768; ++d) {
        const float w0 = W[d * 512 + tid];
        const float w1 = W[d * 512 + 256 + tid];
        #pragma unroll
        for (int q = 0; q < 8; ++q) {
            const float a = a_lds[q * 768 + d];   // broadcast, conflict-free
            acc0[q] = fmaf(a, w0, acc0[q]);
            acc1[q] = fmaf(a, w1, acc1[q]);
        }
    }
    const float b0 = bias[tid], b1 = bias[256 + tid];
    #pragma unroll
    for (int q = 0; q < 8; ++q) {
        kw_lds[q * 512 + tid]       = acc0[q] + b0;
        kw_lds[q * 512 + 256 + tid] = acc1[q] + b1;
    }
    __syncthreads();

    const int w = tid >> 6, lane = tid & 63;
    for (int qq = 0; qq < 2; ++qq) {
        const int q = w + qq * 4;
        float ss = 0.f;
        #pragma unroll
        for (int i = 0; i < 8; ++i) { const float x = kw_lds[q * 512 + lane + i * 64]; ss = fmaf(x, x, ss); }
        #pragma unroll
        for (int o = 1; o < 64; o <<= 1) ss += __shfl_xor(ss, o);
        if (lane == 0) rn_lds[q] = 1.0f / fmaxf(sqrtf(ss), 1e-8f);
    }
    __syncthreads();
    #pragma unroll
    for (int i = 0; i < 16; ++i) {
        const int idx = i * 256 + tid;
        const int q = idx >> 9;
        kwn[(q0 + q) * 512 + (idx & 511)] = (bf16)(kw_lds[idx] * rn_lds[q]);
    }
}

// ---------------- Kernel B: one-pass emb prep --------------------------------
// Per block: 64 v-rows. Produces:
//   rs[v]   = 10/max(||e_v||,eps)   (fp32-exact norms, read from fp32 emb)
//   embS    frag-major for S-phase B: frag = (v_tile= v>>4)*16 + kf(=k/32),
//           1KB frag; element for lane l: [v=vt*16+(l&15)][k = kf*32+(l>>4)*8+j]
//   embT    frag-major for PV-phase B: frag = (kv= v>>5)*32 + tt(=t>>4),
//           element for lane l: [t=tt*16+(l&15)][vloc offset (l>>4)*8+j]
// LDS tile 64x512 bf16 with XOR-swizzled 16B granules (granule' = g ^ (r&7)).
__global__ __launch_bounds__(256) void k_prep(const float* __restrict__ emb,
        bf16* __restrict__ embS, bf16* __restrict__ embT, float* __restrict__ rs) {
    __shared__ unsigned short tile[64 * 512];
    const int tid = threadIdx.x;
    const int b = blockIdx.x;
    const int v0 = b * 64;

    // 1: coalesced load + bf16 convert + swizzled LDS store
    const float4* src = (const float4*)(emb + (size_t)v0 * 512);
    #pragma unroll
    for (int i = 0; i < 32; ++i) {
        const int L = i * 256 + tid;           // float4 index in 64x128
        const int r = L >> 7, c4 = L & 127;
        const float4 x = src[L];
        const int g = c4 >> 1, half = c4 & 1;
        ushort4 u;
        u.x = __builtin_bit_cast(unsigned short, (bf16)x.x);
        u.y = __builtin_bit_cast(unsigned short, (bf16)x.y);
        u.z = __builtin_bit_cast(unsigned short, (bf16)x.z);
        u.w = __builtin_bit_cast(unsigned short, (bf16)x.w);
        *(ushort4*)&tile[r * 512 + (((g ^ (r & 7)) << 3) + half * 4)] = u;
    }
    // 2: fp32-exact row norms (L2-hot re-read), 4 threads per row
    {
        const int row = tid >> 2, quarter = tid & 3;
        const float4* rsrc = (const float4*)(emb + (size_t)(v0 + row) * 512 + quarter * 128);
        float ss = 0.f;
        #pragma unroll
        for (int k = 0; k < 32; ++k) {
            const float4 x = rsrc[k];
            ss += x.x * x.x + x.y * x.y + x.z * x.z + x.w * x.w;
        }
        ss += __shfl_xor(ss, 1);
        ss += __shfl_xor(ss, 2);
        if (quarter == 0) rs[v0 + row] = 10.0f / fmaxf(sqrtf(ss), 1e-8f);  // folds 1/TEMP
    }
    __syncthreads();

    // 3: embS frag-major (uint4 LDS reads, fully coalesced global writes)
    #pragma unroll
    for (int i = 0; i < 16; ++i) {
        const int F = i * 256 + tid;           // out granule 0..4095
        const int frag = F >> 6, l = F & 63;
        const int vt = frag >> 4, kf = frag & 15;
        const int lm = l & 15, lg = l >> 4;
        const int r = vt * 16 + lm, g = kf * 4 + lg;
        const uint4 d = *(const uint4*)&tile[r * 512 + ((g ^ (r & 7)) << 3)];
        *(uint4*)((unsigned short*)embS + ((size_t)(b * 4 + vt) * 16 + kf) * 512 + l * 8) = d;
    }
    // 4: embT frag-major (transpose gather from LDS, coalesced writes)
    #pragma unroll
    for (int i = 0; i < 16; ++i) {
        const int F = i * 256 + tid;
        const int frag = F >> 6, l = F & 63;
        const int kvl = frag >> 5, tt = frag & 31;
        const int lm = l & 15, lg = l >> 4;
        const int t = tt * 16 + lm;
        unsigned short e[8];
        #pragma unroll
        for (int j = 0; j < 8; ++j) {
            const int r = kvl * 32 + lg * 8 + j;
            e[j] = tile[r * 512 + ((((t >> 3) ^ (r & 7)) << 3) + (t & 7))];
        }
        uint4 o;
        o.x = (unsigned)e[0] | ((unsigned)e[1] << 16);
        o.y = (unsigned)e[2] | ((unsigned)e[3] << 16);
        o.z = (unsigned)e[4] | ((unsigned)e[5] << 16);
        o.w = (unsigned)e[6] | ((unsigned)e[7] << 16);
        const int kvg = b * 2 + kvl;           // global v/32 index
        *(uint4*)((unsigned short*)embT + ((size_t)kvg * 32 + tt) * 512 + l * 8) = o;
    }
}

// ---------------- Kernel C: fused scores -> exp -> P@E accumulate ------------
// Grid 1024 = 32 q-tiles x 32 v-splits (split in LOW bits -> co-XCD WGs stream
// the same chunks -> L2 reuse). All B-fragments are frag-major: one wave load
// = one coalesced 1KB block.
__global__ __launch_bounds__(256, 3) void k_attn(const bf16* __restrict__ kwn,
        const bf16* __restrict__ embS, const bf16* __restrict__ embT,
        const float* __restrict__ rs, float* __restrict__ Oacc,
        float* __restrict__ Lsum) {
    __shared__ unsigned short Qlds[32 * 520];   // 32 q-rows, padded pitch
    __shared__ unsigned short Plds[16 * 512];   // P in A-frag-major layout, 16KB
    const int tid = threadIdx.x;
    const int s = blockIdx.x & (NSPLIT - 1), qt = blockIdx.x / NSPLIT;
    const int q0 = qt * 32;
    const int wv = tid >> 6, lane = tid & 63, lm = lane & 15, lg = lane >> 4;

    {   // stage Q tile (32x512 bf16)
        const uint4* src = (const uint4*)(kwn + q0 * 512);
        #pragma unroll
        for (int i = 0; i < 8; ++i) {
            const int L = (i * 256 + tid) * 8;
            *(uint4*)&Qlds[(L >> 9) * 520 + (L & 511)] = src[i * 256 + tid];
        }
    }
    __syncthreads();

    const f32x4 zero4 = {0.f, 0.f, 0.f, 0.f};
    f32x4 acc[2][8];                       // O: [mb 16q][nb 16t] over T-slice 128
    #pragma unroll
    for (int a = 0; a < 2; ++a)
        #pragma unroll
        for (int b = 0; b < 8; ++b) acc[a][b] = zero4;
    float lacc[2][4] = {{0.f,0.f,0.f,0.f},{0.f,0.f,0.f,0.f}};

    const int c0 = (s * NCH) / NSPLIT, c1 = ((s + 1) * NCH) / NSPLIT;
    for (int c = c0; c < c1; ++c) {
        // ---- S = Qn @ En^T (per wave: 32q x 64v, K=512) ----
        f32x4 sacc[2][4];
        #pragma unroll
        for (int a = 0; a < 2; ++a)
            #pragma unroll
            for (int b = 0; b < 4; ++b) sacc[a][b] = zero4;
        const bf16* Eb = embS + ((size_t)(c * 16 + wv * 4) * 16) * 512 + lane * 8;
        #pragma unroll
        for (int kf = 0; kf < 16; ++kf) {
            const bf16x8 aq0 = *(const bf16x8*)&Qlds[lm * 520 + kf * 32 + lg * 8];
            const bf16x8 aq1 = *(const bf16x8*)&Qlds[(16 + lm) * 520 + kf * 32 + lg * 8];
            #pragma unroll
            for (int nb = 0; nb < 4; ++nb) {
                const bf16x8 bfr = *(const bf16x8*)(Eb + (nb * 16 + kf) * 512);
                sacc[0][nb] = __builtin_amdgcn_mfma_f32_16x16x32_bf16(aq0, bfr, sacc[0][nb], 0, 0, 0);
                sacc[1][nb] = __builtin_amdgcn_mfma_f32_16x16x32_bf16(aq1, bfr, sacc[1][nb], 0, 0, 0);
            }
        }
        // ---- p = exp(s * rs[v]); scatter into Plds in A-frag layout ----
        #pragma unroll
        for (int nb = 0; nb < 4; ++nb) {
            const float rsv = rs[c * 256 + wv * 64 + nb * 16 + lm];
            const int kfg = 2 * wv + (nb >> 1);
            const int hi = 2 * (nb & 1) + (lm >> 3);
            const int jj = lm & 7;
            #pragma unroll
            for (int mb = 0; mb < 2; ++mb) {
                const int fragbase = (mb * 8 + kfg) * 512;
                #pragma unroll
                for (int r = 0; r < 4; ++r) {
                    const float p = __expf(sacc[mb][nb][r] * rsv);
                    const bf16 pb = (bf16)p;
                    lacc[mb][r] += (float)pb;   // use rounded value for consistency
                    const int ldest = (lg * 4 + r) + 16 * hi;
                    Plds[fragbase + ldest * 8 + jj] = __builtin_bit_cast(unsigned short, pb);
                }
            }
        }
        __syncthreads();                        // P fully written
        bf16x8 pf[2][8];
        #pragma unroll
        for (int mb = 0; mb < 2; ++mb)
            #pragma unroll
            for (int kf = 0; kf < 8; ++kf)
                pf[mb][kf] = *(const bf16x8*)&Plds[(mb * 8 + kf) * 512 + lane * 8];
        __syncthreads();                        // everyone loaded P; reuse next iter
        // ---- O += P @ E (per wave: 32q x 128t, K=256) ----
        const bf16* ETb = embT + ((size_t)(c * 8) * 32 + wv * 8) * 512 + lane * 8;
        #pragma unroll
        for (int nb = 0; nb < 8; ++nb) {
            #pragma unroll
            for (int kf = 0; kf < 8; ++kf) {
                const bf16x8 bfr = *(const bf16x8*)(ETb + (kf * 32 + nb) * 512);
                acc[0][nb] = __builtin_amdgcn_mfma_f32_16x16x32_bf16(pf[0][kf], bfr, acc[0][nb], 0, 0, 0);
                acc[1][nb] = __builtin_amdgcn_mfma_f32_16x16x32_bf16(pf[1][kf], bfr, acc[1][nb], 0, 0, 0);
            }
        }
    }

    // ---- combine partials across v-splits ----
    #pragma unroll
    for (int mb = 0; mb < 2; ++mb)
        #pragma unroll
        for (int nb = 0; nb < 8; ++nb)
            #pragma unroll
            for (int r = 0; r < 4; ++r) {
                const int q = q0 + mb * 16 + lg * 4 + r;
                const int t = wv * 128 + nb * 16 + lm;
                atomicAdd(&Oacc[q * 512 + t], acc[mb][nb][r]);
            }
    #pragma unroll
    for (int mb = 0; mb < 2; ++mb)
        #pragma unroll
        for (int r = 0; r < 4; ++r) {
            float sum = lacc[mb][r];
            sum += __shfl_xor(sum, 1);
            sum += __shfl_xor(sum, 2);
            sum += __shfl_xor(sum, 4);
            sum += __shfl_xor(sum, 8);
            if (lm == 0) atomicAdd(&Lsum[q0 + mb * 16 + lg * 4 + r], sum);
        }
}

// ---------------- Kernel D: out = Oacc / Lsum --------------------------------
__global__ __launch_bounds__(256) void k_final(const float* __restrict__ Oacc,
        const float* __restrict__ Lsum, float* __restrict__ out) {
    const int i = blockIdx.x * 256 + threadIdx.x;   // float4 index, 131072 total
    const float4 o = ((const float4*)Oacc)[i];
    const float inv = 1.0f / Lsum[i >> 7];          // 128 float4 per row
    float4 r;
    r.x = o.x * inv; r.y = o.y * inv; r.z = o.z * inv; r.w = o.w * inv;
    ((float4*)out)[i] = r;
}

// ---------------- launcher ---------------------------------------------------
// ws layout (bytes) — total 104,535,040 (same footprint as round 1):
//   0        kwn   bf16 [1024*512]          1,048,576
//   1048576  rs    f32  [49408]               197,632
//   1246208  Oacc  f32  [1024*512]          2,097,152   (zeroed each launch)
//   3343360  Lsum  f32  [1024]                   4,096   (zeroed each launch)
//   3347456  embS  bf16 frag-major          50,593,792
//   53941248 embT  bf16 frag-major          50,593,792
extern "C" void kernel_launch(void* const* d_in, const int* in_sizes, int n_in,
                              void* d_out, int out_size, void* d_ws, size_t ws_size,
                              hipStream_t stream) {
    const float* audio = (const float*)d_in[0];
    const float* W     = (const float*)d_in[1];
    const float* bias  = (const float*)d_in[2];
    const float* emb   = (const float*)d_in[3];
    float* out = (float*)d_out;
    char* ws = (char*)d_ws;

    bf16*  kwn  = (bf16*)(ws);
    float* rs   = (float*)(ws + 1048576);
    float* Oacc = (float*)(ws + 1246208);
    float* Lsum = (float*)(ws + 3343360);
    bf16*  embS = (bf16*)(ws + 3347456);
    bf16*  embT = (bf16*)(ws + 53941248);

    hipMemsetAsync(ws + 1246208, 0, 2097152 + 4096, stream);   // Oacc + Lsum
    k_proj<<<128, 256, 0, stream>>>(audio, W, bias, kwn);
    k_prep<<<VDIM / 64, 256, 0, stream>>>(emb, embS, embT, rs);
    k_attn<<<NQT * NSPLIT, 256, 0, stream>>>(kwn, embS, embT, rs, Oacc, Lsum);
    k_final<<<(out_size / 4) / 256, 256, 0, stream>>>(Oacc, Lsum, out);
}

// Round 3
// 544.007 us; speedup vs baseline: 1.4292x; 1.4292x over previous
//
#include <hip/hip_runtime.h>
#include <math.h>

// Problem constants: B=128,N=8 -> M=1024 rows; D=768; T=512; V=49408
#define VDIM    49408
#define NCH     193          // 49408 / 256 v-chunks
#define NSPLIT  16           // V splits (low bits of blockIdx -> same split => same XCD)
#define NQT     32           // 1024 / 32 query tiles

typedef __bf16 bf16;
typedef __bf16 bf16x8 __attribute__((ext_vector_type(8)));
typedef float  f32x4  __attribute__((ext_vector_type(4)));

// ---------------- Kernel A: kw = audio@W + b, row-normalize -> kwn (bf16) ----
// 256 blocks x 256 thr, 4 query rows per block (full CU coverage; W is L2-hot).
__global__ __launch_bounds__(256) void k_proj(const float* __restrict__ audio,
        const float* __restrict__ W, const float* __restrict__ bias,
        bf16* __restrict__ kwn) {
    __shared__ float a_lds[4 * 768];
    __shared__ float kw_lds[4 * 512];
    __shared__ float rn_lds[4];
    const int tid = threadIdx.x;
    const int q0 = blockIdx.x * 4;

    const float4* asrc = (const float4*)(audio + q0 * 768);
    float4* adst = (float4*)a_lds;
    #pragma unroll
    for (int i = 0; i < 3; ++i) adst[i * 256 + tid] = asrc[i * 256 + tid];
    __syncthreads();

    float acc0[4] = {0.f, 0.f, 0.f, 0.f}, acc1[4] = {0.f, 0.f, 0.f, 0.f};
    #pragma unroll 4
    for (int d = 0; d < 768; ++d) {
        const float w0 = W[d * 512 + tid];
        const float w1 = W[d * 512 + 256 + tid];
        #pragma unroll
        for (int q = 0; q < 4; ++q) {
            const float a = a_lds[q * 768 + d];   // broadcast, conflict-free
            acc0[q] = fmaf(a, w0, acc0[q]);
            acc1[q] = fmaf(a, w1, acc1[q]);
        }
    }
    const float b0 = bias[tid], b1 = bias[256 + tid];
    #pragma unroll
    for (int q = 0; q < 4; ++q) {
        kw_lds[q * 512 + tid]       = acc0[q] + b0;
        kw_lds[q * 512 + 256 + tid] = acc1[q] + b1;
    }
    __syncthreads();

    const int w = tid >> 6, lane = tid & 63;
    {   // wave w handles row w
        float ss = 0.f;
        #pragma unroll
        for (int i = 0; i < 8; ++i) { const float x = kw_lds[w * 512 + lane + i * 64]; ss = fmaf(x, x, ss); }
        #pragma unroll
        for (int o = 1; o < 64; o <<= 1) ss += __shfl_xor(ss, o);
        if (lane == 0) rn_lds[w] = 1.0f / fmaxf(sqrtf(ss), 1e-8f);
    }
    __syncthreads();
    #pragma unroll
    for (int i = 0; i < 8; ++i) {
        const int idx = i * 256 + tid;
        const int q = idx >> 9;
        kwn[(q0 + q) * 512 + (idx & 511)] = (bf16)(kw_lds[idx] * rn_lds[q]);
    }
}

// ---------------- Kernel B: one-pass emb prep --------------------------------
// Per block: 64 v-rows, single fp32 read of emb. Produces rs (exact fp32 norms,
// computed in-register during the load pass), embS (S-phase B-frag-major) and
// embT (PV-phase B-frag-major). LDS tile XOR-swizzled in 16B granules.
__global__ __launch_bounds__(256) void k_prep(const float* __restrict__ emb,
        bf16* __restrict__ embS, bf16* __restrict__ embT, float* __restrict__ rs) {
    __shared__ unsigned short tile[64 * 512];
    __shared__ float pnorm[64 * 2];
    const int tid = threadIdx.x;
    const int b = blockIdx.x;
    const int v0 = b * 64;
    const int lane = tid & 63;
    const int p = (tid >> 6) & 1;          // wave parity within row

    // 1: coalesced load + fp32 norm partials + bf16 convert + swizzled LDS store
    const float4* src = (const float4*)(emb + (size_t)v0 * 512);
    #pragma unroll
    for (int i = 0; i < 32; ++i) {
        const int L = i * 256 + tid;           // float4 index in 64x128
        const int r = L >> 7, c4 = L & 127;    // whole wave shares one row r
        const float4 x = src[L];
        float ss = x.x * x.x + x.y * x.y + x.z * x.z + x.w * x.w;
        #pragma unroll
        for (int o = 1; o < 64; o <<= 1) ss += __shfl_xor(ss, o);
        if (lane == 0) pnorm[r * 2 + p] = ss;
        const int g = c4 >> 1, half = c4 & 1;
        ushort4 u;
        u.x = __builtin_bit_cast(unsigned short, (bf16)x.x);
        u.y = __builtin_bit_cast(unsigned short, (bf16)x.y);
        u.z = __builtin_bit_cast(unsigned short, (bf16)x.z);
        u.w = __builtin_bit_cast(unsigned short, (bf16)x.w);
        *(ushort4*)&tile[r * 512 + (((g ^ (r & 7)) << 3) + half * 4)] = u;
    }
    __syncthreads();
    if (tid < 64) {
        const float ss = pnorm[tid * 2] + pnorm[tid * 2 + 1];
        rs[v0 + tid] = 10.0f / fmaxf(sqrtf(ss), 1e-8f);   // folds 1/TEMP
    }

    // 2: embS frag-major (uint4 LDS reads, fully coalesced global writes)
    #pragma unroll
    for (int i = 0; i < 16; ++i) {
        const int F = i * 256 + tid;           // out granule 0..4095
        const int frag = F >> 6, l = F & 63;
        const int vt = frag >> 4, kf = frag & 15;
        const int lm = l & 15, lg = l >> 4;
        const int r = vt * 16 + lm, g = kf * 4 + lg;
        const uint4 d = *(const uint4*)&tile[r * 512 + ((g ^ (r & 7)) << 3)];
        *(uint4*)((unsigned short*)embS + ((size_t)(b * 4 + vt) * 16 + kf) * 512 + l * 8) = d;
    }
    // 3: embT frag-major (transpose gather from LDS, coalesced writes)
    #pragma unroll
    for (int i = 0; i < 16; ++i) {
        const int F = i * 256 + tid;
        const int frag = F >> 6, l = F & 63;
        const int kvl = frag >> 5, tt = frag & 31;
        const int lm = l & 15, lg = l >> 4;
        const int t = tt * 16 + lm;
        unsigned short e[8];
        #pragma unroll
        for (int j = 0; j < 8; ++j) {
            const int r = kvl * 32 + lg * 8 + j;
            e[j] = tile[r * 512 + ((((t >> 3) ^ (r & 7)) << 3) + (t & 7))];
        }
        uint4 o;
        o.x = (unsigned)e[0] | ((unsigned)e[1] << 16);
        o.y = (unsigned)e[2] | ((unsigned)e[3] << 16);
        o.z = (unsigned)e[4] | ((unsigned)e[5] << 16);
        o.w = (unsigned)e[6] | ((unsigned)e[7] << 16);
        const int kvg = b * 2 + kvl;           // global v/32 index
        *(uint4*)((unsigned short*)embT + ((size_t)kvg * 32 + tt) * 512 + l * 8) = o;
    }
}

// ---------------- Kernel C: producer/consumer fused attention ----------------
// 512 threads = 8 waves. Waves 0-3 (producers): S = Qn@En^T -> exp -> P-frags
// into Plds ring buffer + Lsum. Waves 4-7 (consumers): O += P @ E from embT.
// One barrier per chunk; producer runs one chunk ahead of consumer.
// Grid 512 = 32 q-tiles x 16 v-splits; split in LOW bits => all 32 q-tiles of
// a split land on one XCD (round-robin) and share its chunk stream in L2.
__global__ __launch_bounds__(512, 4) void k_attn(const bf16* __restrict__ kwn,
        const bf16* __restrict__ embS, const bf16* __restrict__ embT,
        const float* __restrict__ rs, float* __restrict__ Oacc,
        float* __restrict__ Lsum) {
    __shared__ unsigned short Qlds[32 * 520];       // 33.3 KB
    __shared__ unsigned short Plds[2 * 16 * 512];   // 32 KB double-buffered ring
    const int tid = threadIdx.x;
    const int s = blockIdx.x & (NSPLIT - 1), qt = blockIdx.x >> 4;
    const int q0 = qt * 32;
    const int wg = tid >> 6, lane = tid & 63, lm = lane & 15, lg = lane >> 4;

    {   // stage Q tile (32x512 bf16), all 8 waves
        const uint4* src = (const uint4*)(kwn + q0 * 512);
        #pragma unroll
        for (int i = 0; i < 4; ++i) {
            const int L = (i * 512 + tid) * 8;
            *(uint4*)&Qlds[(L >> 9) * 520 + (L & 511)] = src[i * 512 + tid];
        }
    }
    __syncthreads();

    const f32x4 zero4 = {0.f, 0.f, 0.f, 0.f};
    f32x4 acc[2][8];                       // consumer O: [mb 16q][nb 16t], t-slice 128
    #pragma unroll
    for (int a = 0; a < 2; ++a)
        #pragma unroll
        for (int bq = 0; bq < 8; ++bq) acc[a][bq] = zero4;

    const int c0 = (s * NCH) / NSPLIT, c1 = ((s + 1) * NCH) / NSPLIT;
    const int n = c1 - c0;
    const int cw = wg - 4;                 // consumer t-slice index

    for (int i = 0; i <= n; ++i) {
        if (wg < 4) {
            if (i < n) {   // -------- producer: chunk c0+i --------
                const int c = c0 + i;
                f32x4 sacc[2][4];
                #pragma unroll
                for (int a = 0; a < 2; ++a)
                    #pragma unroll
                    for (int bq = 0; bq < 4; ++bq) sacc[a][bq] = zero4;
                const bf16* Eb = embS + ((size_t)(c * 16 + wg * 4) * 16) * 512 + lane * 8;
                #pragma unroll
                for (int kf = 0; kf < 16; ++kf) {
                    const bf16x8 aq0 = *(const bf16x8*)&Qlds[lm * 520 + kf * 32 + lg * 8];
                    const bf16x8 aq1 = *(const bf16x8*)&Qlds[(16 + lm) * 520 + kf * 32 + lg * 8];
                    #pragma unroll
                    for (int nb = 0; nb < 4; ++nb) {
                        const bf16x8 bfr = *(const bf16x8*)(Eb + (nb * 16 + kf) * 512);
                        sacc[0][nb] = __builtin_amdgcn_mfma_f32_16x16x32_bf16(aq0, bfr, sacc[0][nb], 0, 0, 0);
                        sacc[1][nb] = __builtin_amdgcn_mfma_f32_16x16x32_bf16(aq1, bfr, sacc[1][nb], 0, 0, 0);
                    }
                }
                // p = exp(s*rs[v]); scatter into Plds ring in A-frag layout
                unsigned short* Pw = Plds + ((i & 1) << 13);
                float lc[2][4] = {{0.f,0.f,0.f,0.f},{0.f,0.f,0.f,0.f}};
                #pragma unroll
                for (int nb = 0; nb < 4; ++nb) {
                    const float rsv = rs[c * 256 + wg * 64 + nb * 16 + lm];
                    const int kfg = 2 * wg + (nb >> 1);
                    const int hi = 2 * (nb & 1) + (lm >> 3);
                    const int jj = lm & 7;
                    #pragma unroll
                    for (int mb = 0; mb < 2; ++mb) {
                        const int fragbase = (mb * 8 + kfg) * 512;
                        #pragma unroll
                        for (int r = 0; r < 4; ++r) {
                            const float pv = __expf(sacc[mb][nb][r] * rsv);
                            const bf16 pb = (bf16)pv;
                            lc[mb][r] += (float)pb;   // rounded value for consistency
                            const int ldest = (lg * 4 + r) + 16 * hi;
                            Pw[fragbase + ldest * 8 + jj] = __builtin_bit_cast(unsigned short, pb);
                        }
                    }
                }
                // per-chunk Lsum contribution (reduce over lm lanes)
                #pragma unroll
                for (int mb = 0; mb < 2; ++mb)
                    #pragma unroll
                    for (int r = 0; r < 4; ++r) {
                        float sum = lc[mb][r];
                        sum += __shfl_xor(sum, 1);
                        sum += __shfl_xor(sum, 2);
                        sum += __shfl_xor(sum, 4);
                        sum += __shfl_xor(sum, 8);
                        if (lm == 0) atomicAdd(&Lsum[q0 + mb * 16 + lg * 4 + r], sum);
                    }
            }
        } else {
            if (i > 0) {   // -------- consumer: chunk c0+i-1 --------
                const int cc = c0 + i - 1;
                const unsigned short* Pb = Plds + (((i - 1) & 1) << 13);
                const bf16* ETb = embT + ((size_t)(cc * 8) * 32 + cw * 8) * 512 + lane * 8;
                #pragma unroll
                for (int kf = 0; kf < 8; ++kf) {
                    const bf16x8 pf0 = *(const bf16x8*)&Pb[kf * 512 + lane * 8];
                    const bf16x8 pf1 = *(const bf16x8*)&Pb[(8 + kf) * 512 + lane * 8];
                    #pragma unroll
                    for (int nb = 0; nb < 8; ++nb) {
                        const bf16x8 bfr = *(const bf16x8*)(ETb + (kf * 32 + nb) * 512);
                        acc[0][nb] = __builtin_amdgcn_mfma_f32_16x16x32_bf16(pf0, bfr, acc[0][nb], 0, 0, 0);
                        acc[1][nb] = __builtin_amdgcn_mfma_f32_16x16x32_bf16(pf1, bfr, acc[1][nb], 0, 0, 0);
                    }
                }
            }
        }
        __syncthreads();
    }

    // ---- consumer epilogue: combine partials across v-splits ----
    if (wg >= 4) {
        #pragma unroll
        for (int mb = 0; mb < 2; ++mb)
            #pragma unroll
            for (int nb = 0; nb < 8; ++nb)
                #pragma unroll
                for (int r = 0; r < 4; ++r) {
                    const int q = q0 + mb * 16 + lg * 4 + r;
                    const int t = cw * 128 + nb * 16 + lm;
                    atomicAdd(&Oacc[q * 512 + t], acc[mb][nb][r]);
                }
    }
}

// ---------------- Kernel D: out = Oacc / Lsum --------------------------------
__global__ __launch_bounds__(256) void k_final(const float* __restrict__ Oacc,
        const float* __restrict__ Lsum, float* __restrict__ out) {
    const int i = blockIdx.x * 256 + threadIdx.x;   // float4 index, 131072 total
    const float4 o = ((const float4*)Oacc)[i];
    const float inv = 1.0f / Lsum[i >> 7];          // 128 float4 per row
    float4 r;
    r.x = o.x * inv; r.y = o.y * inv; r.z = o.z * inv; r.w = o.w * inv;
    ((float4*)out)[i] = r;
}

// ---------------- launcher ---------------------------------------------------
// ws layout (bytes) — total 104,535,040 (unchanged; known to fit):
//   0        kwn   bf16 [1024*512]          1,048,576
//   1048576  rs    f32  [49408]               197,632
//   1246208  Oacc  f32  [1024*512]          2,097,152   (zeroed each launch)
//   3343360  Lsum  f32  [1024]                   4,096   (zeroed each launch)
//   3347456  embS  bf16 frag-major          50,593,792
//   53941248 embT  bf16 frag-major          50,593,792
extern "C" void kernel_launch(void* const* d_in, const int* in_sizes, int n_in,
                              void* d_out, int out_size, void* d_ws, size_t ws_size,
                              hipStream_t stream) {
    const float* audio = (const float*)d_in[0];
    const float* W     = (const float*)d_in[1];
    const float* bias  = (const float*)d_in[2];
    const float* emb   = (const float*)d_in[3];
    float* out = (float*)d_out;
    char* ws = (char*)d_ws;

    bf16*  kwn  = (bf16*)(ws);
    float* rs   = (float*)(ws + 1048576);
    float* Oacc = (float*)(ws + 1246208);
    float* Lsum = (float*)(ws + 3343360);
    bf16*  embS = (bf16*)(ws + 3347456);
    bf16*  embT = (bf16*)(ws + 53941248);

    hipMemsetAsync(ws + 1246208, 0, 2097152 + 4096, stream);   // Oacc + Lsum
    k_proj<<<256, 256, 0, stream>>>(audio, W, bias, kwn);
    k_prep<<<VDIM / 64, 256, 0, stream>>>(emb, embS, embT, rs);
    k_attn<<<NQT * NSPLIT, 512, 0, stream>>>(kwn, embS, embT, rs, Oacc, Lsum);
    k_final<<<(out_size / 4) / 256, 256, 0, stream>>>(Oacc, Lsum, out);
}

// Round 5
// 515.872 us; speedup vs baseline: 1.5071x; 1.0545x over previous
//
#include <hip/hip_runtime.h>
#include <math.h>

// Problem constants: B=128,N=8 -> M=1024 rows; D=768; T=512; V=49408
#define VDIM    49408
#define NCH     193          // 49408 / 256 v-chunks
#define NSPLIT  16           // V splits (low bits of blockIdx -> same split => same XCD)
#define NQT     32           // 1024 / 32 query tiles

typedef __bf16 bf16;
typedef __bf16 bf16x8 __attribute__((ext_vector_type(8)));
typedef float  f32x4  __attribute__((ext_vector_type(4)));

// ---------------- Kernel A: kw = audio@W + b, row-normalize -> kwn (bf16) ----
__global__ __launch_bounds__(256) void k_proj(const float* __restrict__ audio,
        const float* __restrict__ W, const float* __restrict__ bias,
        bf16* __restrict__ kwn) {
    __shared__ float a_lds[4 * 768];
    __shared__ float kw_lds[4 * 512];
    __shared__ float rn_lds[4];
    const int tid = threadIdx.x;
    const int q0 = blockIdx.x * 4;

    const float4* asrc = (const float4*)(audio + q0 * 768);
    float4* adst = (float4*)a_lds;
    #pragma unroll
    for (int i = 0; i < 3; ++i) adst[i * 256 + tid] = asrc[i * 256 + tid];
    __syncthreads();

    float acc0[4] = {0.f, 0.f, 0.f, 0.f}, acc1[4] = {0.f, 0.f, 0.f, 0.f};
    #pragma unroll 4
    for (int d = 0; d < 768; ++d) {
        const float w0 = W[d * 512 + tid];
        const float w1 = W[d * 512 + 256 + tid];
        #pragma unroll
        for (int q = 0; q < 4; ++q) {
            const float a = a_lds[q * 768 + d];   // broadcast, conflict-free
            acc0[q] = fmaf(a, w0, acc0[q]);
            acc1[q] = fmaf(a, w1, acc1[q]);
        }
    }
    const float b0 = bias[tid], b1 = bias[256 + tid];
    #pragma unroll
    for (int q = 0; q < 4; ++q) {
        kw_lds[q * 512 + tid]       = acc0[q] + b0;
        kw_lds[q * 512 + 256 + tid] = acc1[q] + b1;
    }
    __syncthreads();

    const int w = tid >> 6, lane = tid & 63;
    {   // wave w handles row w
        float ss = 0.f;
        #pragma unroll
        for (int i = 0; i < 8; ++i) { const float x = kw_lds[w * 512 + lane + i * 64]; ss = fmaf(x, x, ss); }
        #pragma unroll
        for (int o = 1; o < 64; o <<= 1) ss += __shfl_xor(ss, o);
        if (lane == 0) rn_lds[w] = 1.0f / fmaxf(sqrtf(ss), 1e-8f);
    }
    __syncthreads();
    #pragma unroll
    for (int i = 0; i < 8; ++i) {
        const int idx = i * 256 + tid;
        const int q = idx >> 9;
        kwn[(q0 + q) * 512 + (idx & 511)] = (bf16)(kw_lds[idx] * rn_lds[q]);
    }
}

// ---------------- Kernel B: one-pass emb prep --------------------------------
__global__ __launch_bounds__(256) void k_prep(const float* __restrict__ emb,
        bf16* __restrict__ embS, bf16* __restrict__ embT, float* __restrict__ rs) {
    __shared__ unsigned short tile[64 * 512];
    __shared__ float pnorm[64 * 2];
    const int tid = threadIdx.x;
    const int b = blockIdx.x;
    const int v0 = b * 64;
    const int lane = tid & 63;
    const int p = (tid >> 6) & 1;          // wave parity within row

    // 1: coalesced load + fp32 norm partials + bf16 convert + swizzled LDS store
    const float4* src = (const float4*)(emb + (size_t)v0 * 512);
    #pragma unroll
    for (int i = 0; i < 32; ++i) {
        const int L = i * 256 + tid;           // float4 index in 64x128
        const int r = L >> 7, c4 = L & 127;    // whole wave shares one row r
        const float4 x = src[L];
        float ss = x.x * x.x + x.y * x.y + x.z * x.z + x.w * x.w;
        #pragma unroll
        for (int o = 1; o < 64; o <<= 1) ss += __shfl_xor(ss, o);
        if (lane == 0) pnorm[r * 2 + p] = ss;
        const int g = c4 >> 1, half = c4 & 1;
        ushort4 u;
        u.x = __builtin_bit_cast(unsigned short, (bf16)x.x);
        u.y = __builtin_bit_cast(unsigned short, (bf16)x.y);
        u.z = __builtin_bit_cast(unsigned short, (bf16)x.z);
        u.w = __builtin_bit_cast(unsigned short, (bf16)x.w);
        *(ushort4*)&tile[r * 512 + (((g ^ (r & 7)) << 3) + half * 4)] = u;
    }
    __syncthreads();
    if (tid < 64) {
        const float ss = pnorm[tid * 2] + pnorm[tid * 2 + 1];
        rs[v0 + tid] = 10.0f / fmaxf(sqrtf(ss), 1e-8f);   // folds 1/TEMP
    }

    // 2: embS frag-major (uint4 LDS reads, fully coalesced global writes)
    #pragma unroll
    for (int i = 0; i < 16; ++i) {
        const int F = i * 256 + tid;           // out granule 0..4095
        const int frag = F >> 6, l = F & 63;
        const int vt = frag >> 4, kf = frag & 15;
        const int lm = l & 15, lg = l >> 4;
        const int r = vt * 16 + lm, g = kf * 4 + lg;
        const uint4 d = *(const uint4*)&tile[r * 512 + ((g ^ (r & 7)) << 3)];
        *(uint4*)((unsigned short*)embS + ((size_t)(b * 4 + vt) * 16 + kf) * 512 + l * 8) = d;
    }
    // 3: embT frag-major (transpose gather from LDS, coalesced writes)
    #pragma unroll
    for (int i = 0; i < 16; ++i) {
        const int F = i * 256 + tid;
        const int frag = F >> 6, l = F & 63;
        const int kvl = frag >> 5, tt = frag & 31;
        const int lm = l & 15, lg = l >> 4;
        const int t = tt * 16 + lm;
        unsigned short e[8];
        #pragma unroll
        for (int j = 0; j < 8; ++j) {
            const int r = kvl * 32 + lg * 8 + j;
            e[j] = tile[r * 512 + ((((t >> 3) ^ (r & 7)) << 3) + (t & 7))];
        }
        uint4 o;
        o.x = (unsigned)e[0] | ((unsigned)e[1] << 16);
        o.y = (unsigned)e[2] | ((unsigned)e[3] << 16);
        o.z = (unsigned)e[4] | ((unsigned)e[5] << 16);
        o.w = (unsigned)e[6] | ((unsigned)e[7] << 16);
        const int kvg = b * 2 + kvl;           // global v/32 index
        *(uint4*)((unsigned short*)embT + ((size_t)kvg * 32 + tt) * 512 + l * 8) = o;
    }
}

// ---------------- Kernel C: producer/consumer with wave-granular flag sync ---
// 512 threads = 8 waves. Waves 0-3 (producers): S = Qn@En^T -> exp -> P-frags
// into a 2-slot LDS ring. Waves 4-7 (consumers): O += P @ E from embT.
// NO per-chunk __syncthreads: monotonic LDS counters (ONE increment per wave —
// lane-0 guarded! R4's all-lane increment was a x64 overcount => race) with
// acquire/release ordering let each wave proceed the moment its dependency is
// met, so producer L2 misses don't convoy the whole workgroup.
__global__ __launch_bounds__(512, 4) void k_attn(const bf16* __restrict__ kwn,
        const bf16* __restrict__ embS, const bf16* __restrict__ embT,
        const float* __restrict__ rs, float* __restrict__ Oacc,
        float* __restrict__ Lsum) {
    __shared__ unsigned short Qlds[32 * 512];       // 32 KB, XOR-swizzled granules
    __shared__ unsigned short Plds[2 * 16 * 512];   // 32 KB, 2-slot ring
    __shared__ int prod_done[2], cons_done[2];
    const int tid = threadIdx.x;
    const int s = blockIdx.x & (NSPLIT - 1), qt = blockIdx.x >> 4;
    const int q0 = qt * 32;
    const int wg = tid >> 6, lane = tid & 63, lm = lane & 15, lg = lane >> 4;

    if (tid < 2) { prod_done[tid] = 0; cons_done[tid] = 0; }
    {   // stage Q tile (32x512 bf16), granule-swizzled: g' = g ^ (q&7)
        const uint4* src = (const uint4*)(kwn + q0 * 512);
        #pragma unroll
        for (int i = 0; i < 4; ++i) {
            const int L = (i * 512 + tid) * 8;
            const int q = L >> 9, g = (L & 511) >> 3;
            *(uint4*)&Qlds[q * 512 + ((g ^ (q & 7)) << 3)] = src[i * 512 + tid];
        }
    }
    __syncthreads();   // covers Q staging + flag init

    const f32x4 zero4 = {0.f, 0.f, 0.f, 0.f};
    const int c0 = (s * NCH) / NSPLIT, c1 = ((s + 1) * NCH) / NSPLIT;
    const int n = c1 - c0;

    if (wg < 4) {
        // ================= producer =================
        float lacc[2][4] = {{0.f,0.f,0.f,0.f},{0.f,0.f,0.f,0.f}};
        for (int i = 0; i < n; ++i) {
            const int c = c0 + i;
            const int slot = i & 1, use = i >> 1;
            // wait: all 4 consumer waves finished previous use of this slot
            while (__hip_atomic_load(&cons_done[slot], __ATOMIC_ACQUIRE,
                                     __HIP_MEMORY_SCOPE_WORKGROUP) < 4 * use)
                __builtin_amdgcn_s_sleep(1);
            f32x4 sacc[2][4];
            #pragma unroll
            for (int a = 0; a < 2; ++a)
                #pragma unroll
                for (int bq = 0; bq < 4; ++bq) sacc[a][bq] = zero4;
            const bf16* Eb = embS + ((size_t)(c * 16 + wg * 4) * 16) * 512 + lane * 8;
            #pragma unroll
            for (int kf = 0; kf < 16; ++kf) {
                const int ga = kf * 4 + lg;
                const bf16x8 aq0 = *(const bf16x8*)&Qlds[lm * 512 + ((ga ^ (lm & 7)) << 3)];
                const bf16x8 aq1 = *(const bf16x8*)&Qlds[(16 + lm) * 512 + ((ga ^ ((16 + lm) & 7)) << 3)];
                #pragma unroll
                for (int nb = 0; nb < 4; ++nb) {
                    const bf16x8 bfr = *(const bf16x8*)(Eb + (nb * 16 + kf) * 512);
                    sacc[0][nb] = __builtin_amdgcn_mfma_f32_16x16x32_bf16(aq0, bfr, sacc[0][nb], 0, 0, 0);
                    sacc[1][nb] = __builtin_amdgcn_mfma_f32_16x16x32_bf16(aq1, bfr, sacc[1][nb], 0, 0, 0);
                }
            }
            // p = exp(s*rs[v]); scatter into ring slot in A-frag layout
            unsigned short* Pw = Plds + (slot << 13);
            #pragma unroll
            for (int nb = 0; nb < 4; ++nb) {
                const float rsv = rs[c * 256 + wg * 64 + nb * 16 + lm];
                const int kfg = 2 * wg + (nb >> 1);
                const int hi = 2 * (nb & 1) + (lm >> 3);
                const int jj = lm & 7;
                #pragma unroll
                for (int mb = 0; mb < 2; ++mb) {
                    const int fragbase = (mb * 8 + kfg) * 512;
                    #pragma unroll
                    for (int r = 0; r < 4; ++r) {
                        const float pv = __expf(sacc[mb][nb][r] * rsv);
                        const bf16 pb = (bf16)pv;
                        lacc[mb][r] += (float)pb;   // rounded value for consistency
                        const int ldest = (lg * 4 + r) + 16 * hi;
                        Pw[fragbase + ldest * 8 + jj] = __builtin_bit_cast(unsigned short, pb);
                    }
                }
            }
            if (lane == 0)   // ONE increment per wave (release drains wave's LDS writes)
                __hip_atomic_fetch_add(&prod_done[slot], 1, __ATOMIC_RELEASE,
                                       __HIP_MEMORY_SCOPE_WORKGROUP);
        }
        // Lsum: one atomic per (mb,r) at the very end
        #pragma unroll
        for (int mb = 0; mb < 2; ++mb)
            #pragma unroll
            for (int r = 0; r < 4; ++r) {
                float sum = lacc[mb][r];
                sum += __shfl_xor(sum, 1);
                sum += __shfl_xor(sum, 2);
                sum += __shfl_xor(sum, 4);
                sum += __shfl_xor(sum, 8);
                if (lm == 0) atomicAdd(&Lsum[q0 + mb * 16 + lg * 4 + r], sum);
            }
    } else {
        // ================= consumer =================
        const int cw = wg - 4;             // t-slice index
        f32x4 acc[2][8];
        #pragma unroll
        for (int a = 0; a < 2; ++a)
            #pragma unroll
            for (int bq = 0; bq < 8; ++bq) acc[a][bq] = zero4;
        for (int i = 0; i < n; ++i) {
            const int cc = c0 + i;
            const int slot = i & 1, use = i >> 1;
            // wait: all 4 producer waves have published chunk i into this slot
            while (__hip_atomic_load(&prod_done[slot], __ATOMIC_ACQUIRE,
                                     __HIP_MEMORY_SCOPE_WORKGROUP) < 4 * (use + 1))
                __builtin_amdgcn_s_sleep(1);
            const unsigned short* Pb = Plds + (slot << 13);
            const bf16* ETb = embT + ((size_t)(cc * 8) * 32 + cw * 8) * 512 + lane * 8;
            #pragma unroll
            for (int kf = 0; kf < 8; ++kf) {
                const bf16x8 pf0 = *(const bf16x8*)&Pb[kf * 512 + lane * 8];
                const bf16x8 pf1 = *(const bf16x8*)&Pb[(8 + kf) * 512 + lane * 8];
                #pragma unroll
                for (int nb = 0; nb < 8; ++nb) {
                    const bf16x8 bfr = *(const bf16x8*)(ETb + (kf * 32 + nb) * 512);
                    acc[0][nb] = __builtin_amdgcn_mfma_f32_16x16x32_bf16(pf0, bfr, acc[0][nb], 0, 0, 0);
                    acc[1][nb] = __builtin_amdgcn_mfma_f32_16x16x32_bf16(pf1, bfr, acc[1][nb], 0, 0, 0);
                }
            }
            if (lane == 0)   // ONE increment per wave (release drains wave's LDS reads)
                __hip_atomic_fetch_add(&cons_done[slot], 1, __ATOMIC_RELEASE,
                                       __HIP_MEMORY_SCOPE_WORKGROUP);
        }
        // epilogue: combine partials across v-splits
        #pragma unroll
        for (int mb = 0; mb < 2; ++mb)
            #pragma unroll
            for (int nb = 0; nb < 8; ++nb)
                #pragma unroll
                for (int r = 0; r < 4; ++r) {
                    const int q = q0 + mb * 16 + lg * 4 + r;
                    const int t = cw * 128 + nb * 16 + lm;
                    atomicAdd(&Oacc[q * 512 + t], acc[mb][nb][r]);
                }
    }
}

// ---------------- Kernel D: out = Oacc / Lsum --------------------------------
__global__ __launch_bounds__(256) void k_final(const float* __restrict__ Oacc,
        const float* __restrict__ Lsum, float* __restrict__ out) {
    const int i = blockIdx.x * 256 + threadIdx.x;   // float4 index, 131072 total
    const float4 o = ((const float4*)Oacc)[i];
    const float inv = 1.0f / Lsum[i >> 7];          // 128 float4 per row
    float4 r;
    r.x = o.x * inv; r.y = o.y * inv; r.z = o.z * inv; r.w = o.w * inv;
    ((float4*)out)[i] = r;
}

// ---------------- launcher ---------------------------------------------------
// ws layout (bytes) — total 104,535,040 (proven to fit):
//   0        kwn   bf16 [1024*512]          1,048,576
//   1048576  rs    f32  [49408]               197,632
//   1246208  Oacc  f32  [1024*512]          2,097,152   (zeroed each launch)
//   3343360  Lsum  f32  [1024]                   4,096   (zeroed each launch)
//   3347456  embS  bf16 frag-major          50,593,792
//   53941248 embT  bf16 frag-major          50,593,792
extern "C" void kernel_launch(void* const* d_in, const int* in_sizes, int n_in,
                              void* d_out, int out_size, void* d_ws, size_t ws_size,
                              hipStream_t stream) {
    const float* audio = (const float*)d_in[0];
    const float* W     = (const float*)d_in[1];
    const float* bias  = (const float*)d_in[2];
    const float* emb   = (const float*)d_in[3];
    float* out = (float*)d_out;
    char* ws = (char*)d_ws;

    bf16*  kwn  = (bf16*)(ws);
    float* rs   = (float*)(ws + 1048576);
    float* Oacc = (float*)(ws + 1246208);
    float* Lsum = (float*)(ws + 3343360);
    bf16*  embS = (bf16*)(ws + 3347456);
    bf16*  embT = (bf16*)(ws + 53941248);

    hipMemsetAsync(ws + 1246208, 0, 2097152 + 4096, stream);   // Oacc + Lsum
    k_proj<<<256, 256, 0, stream>>>(audio, W, bias, kwn);
    k_prep<<<VDIM / 64, 256, 0, stream>>>(emb, embS, embT, rs);
    k_attn<<<NQT * NSPLIT, 512, 0, stream>>>(kwn, embS, embT, rs, Oacc, Lsum);
    k_final<<<(out_size / 4) / 256, 256, 0, stream>>>(Oacc, Lsum, out);
}

// Round 6
// 432.966 us; speedup vs baseline: 1.7957x; 1.1915x over previous
//
#include <hip/hip_runtime.h>
#include <math.h>

// Problem constants: B=128,N=8 -> M=1024 rows; D=768; T=512; V=49408
#define VDIM    49408
#define NCH     193          // 49408 / 256 v-chunks
#define NSPLIT  16           // V splits (low bits of blockIdx -> same split => same XCD)
#define NQT     32           // 1024 / 32 query tiles

typedef __bf16 bf16;
typedef __bf16 bf16x8 __attribute__((ext_vector_type(8)));
typedef float  f32x4  __attribute__((ext_vector_type(4)));

// ---------------- Kernel A: kw = audio@W + b, row-normalize -> kwn (bf16) ----
__global__ __launch_bounds__(256) void k_proj(const float* __restrict__ audio,
        const float* __restrict__ W, const float* __restrict__ bias,
        bf16* __restrict__ kwn) {
    __shared__ float a_lds[4 * 768];
    __shared__ float kw_lds[4 * 512];
    __shared__ float rn_lds[4];
    const int tid = threadIdx.x;
    const int q0 = blockIdx.x * 4;

    const float4* asrc = (const float4*)(audio + q0 * 768);
    float4* adst = (float4*)a_lds;
    #pragma unroll
    for (int i = 0; i < 3; ++i) adst[i * 256 + tid] = asrc[i * 256 + tid];
    __syncthreads();

    float acc0[4] = {0.f, 0.f, 0.f, 0.f}, acc1[4] = {0.f, 0.f, 0.f, 0.f};
    #pragma unroll 4
    for (int d = 0; d < 768; ++d) {
        const float w0 = W[d * 512 + tid];
        const float w1 = W[d * 512 + 256 + tid];
        #pragma unroll
        for (int q = 0; q < 4; ++q) {
            const float a = a_lds[q * 768 + d];   // broadcast, conflict-free
            acc0[q] = fmaf(a, w0, acc0[q]);
            acc1[q] = fmaf(a, w1, acc1[q]);
        }
    }
    const float b0 = bias[tid], b1 = bias[256 + tid];
    #pragma unroll
    for (int q = 0; q < 4; ++q) {
        kw_lds[q * 512 + tid]       = acc0[q] + b0;
        kw_lds[q * 512 + 256 + tid] = acc1[q] + b1;
    }
    __syncthreads();

    const int w = tid >> 6, lane = tid & 63;
    {   // wave w handles row w
        float ss = 0.f;
        #pragma unroll
        for (int i = 0; i < 8; ++i) { const float x = kw_lds[w * 512 + lane + i * 64]; ss = fmaf(x, x, ss); }
        #pragma unroll
        for (int o = 1; o < 64; o <<= 1) ss += __shfl_xor(ss, o);
        if (lane == 0) rn_lds[w] = 1.0f / fmaxf(sqrtf(ss), 1e-8f);
    }
    __syncthreads();
    #pragma unroll
    for (int i = 0; i < 8; ++i) {
        const int idx = i * 256 + tid;
        const int q = idx >> 9;
        kwn[(q0 + q) * 512 + (idx & 511)] = (bf16)(kw_lds[idx] * rn_lds[q]);
    }
}

// ---------------- Kernel B: one-pass emb prep --------------------------------
__global__ __launch_bounds__(256) void k_prep(const float* __restrict__ emb,
        bf16* __restrict__ embS, bf16* __restrict__ embT, float* __restrict__ rs) {
    __shared__ unsigned short tile[64 * 512];
    __shared__ float pnorm[64 * 2];
    const int tid = threadIdx.x;
    const int b = blockIdx.x;
    const int v0 = b * 64;
    const int lane = tid & 63;
    const int p = (tid >> 6) & 1;          // wave parity within row

    // 1: coalesced load + fp32 norm partials + bf16 convert + swizzled LDS store
    const float4* src = (const float4*)(emb + (size_t)v0 * 512);
    #pragma unroll
    for (int i = 0; i < 32; ++i) {
        const int L = i * 256 + tid;           // float4 index in 64x128
        const int r = L >> 7, c4 = L & 127;    // whole wave shares one row r
        const float4 x = src[L];
        float ss = x.x * x.x + x.y * x.y + x.z * x.z + x.w * x.w;
        #pragma unroll
        for (int o = 1; o < 64; o <<= 1) ss += __shfl_xor(ss, o);
        if (lane == 0) pnorm[r * 2 + p] = ss;
        const int g = c4 >> 1, half = c4 & 1;
        ushort4 u;
        u.x = __builtin_bit_cast(unsigned short, (bf16)x.x);
        u.y = __builtin_bit_cast(unsigned short, (bf16)x.y);
        u.z = __builtin_bit_cast(unsigned short, (bf16)x.z);
        u.w = __builtin_bit_cast(unsigned short, (bf16)x.w);
        *(ushort4*)&tile[r * 512 + (((g ^ (r & 7)) << 3) + half * 4)] = u;
    }
    __syncthreads();
    if (tid < 64) {
        const float ss = pnorm[tid * 2] + pnorm[tid * 2 + 1];
        rs[v0 + tid] = 10.0f / fmaxf(sqrtf(ss), 1e-8f);   // folds 1/TEMP
    }

    // 2: embS frag-major (uint4 LDS reads, fully coalesced global writes)
    #pragma unroll
    for (int i = 0; i < 16; ++i) {
        const int F = i * 256 + tid;           // out granule 0..4095
        const int frag = F >> 6, l = F & 63;
        const int vt = frag >> 4, kf = frag & 15;
        const int lm = l & 15, lg = l >> 4;
        const int r = vt * 16 + lm, g = kf * 4 + lg;
        const uint4 d = *(const uint4*)&tile[r * 512 + ((g ^ (r & 7)) << 3)];
        *(uint4*)((unsigned short*)embS + ((size_t)(b * 4 + vt) * 16 + kf) * 512 + l * 8) = d;
    }
    // 3: embT frag-major (transpose gather from LDS, coalesced writes)
    #pragma unroll
    for (int i = 0; i < 16; ++i) {
        const int F = i * 256 + tid;
        const int frag = F >> 6, l = F & 63;
        const int kvl = frag >> 5, tt = frag & 31;
        const int lm = l & 15, lg = l >> 4;
        const int t = tt * 16 + lm;
        unsigned short e[8];
        #pragma unroll
        for (int j = 0; j < 8; ++j) {
            const int r = kvl * 32 + lg * 8 + j;
            e[j] = tile[r * 512 + ((((t >> 3) ^ (r & 7)) << 3) + (t & 7))];
        }
        uint4 o;
        o.x = (unsigned)e[0] | ((unsigned)e[1] << 16);
        o.y = (unsigned)e[2] | ((unsigned)e[3] << 16);
        o.z = (unsigned)e[4] | ((unsigned)e[5] << 16);
        o.w = (unsigned)e[6] | ((unsigned)e[7] << 16);
        const int kvg = b * 2 + kvl;           // global v/32 index
        *(uint4*)((unsigned short*)embT + ((size_t)kvg * 32 + tt) * 512 + l * 8) = o;
    }
}

// ---------------- Kernel C: producer/consumer, deep-MLP-pipelined loads ------
// 512 threads = 8 waves; waves 0-3 produce P (S=QE^T -> exp), waves 4-7 consume
// (O += P@E). Wave-granular flag sync (lane-0-guarded monotonic counters).
// R6: (a) producer computes ALL of S before waiting for the slot (E loads and
// MFMAs are flag-independent); (b) B-frags batch-loaded 16 (prod) / 8 (cons)
// at a time into register arrays -> 8-16 KB in flight per wave instead of ~1;
// (c) consumer prefetches its first E batch before the flag wait.
__global__ __launch_bounds__(512, 4) void k_attn(const bf16* __restrict__ kwn,
        const bf16* __restrict__ embS, const bf16* __restrict__ embT,
        const float* __restrict__ rs, float* __restrict__ Oacc,
        float* __restrict__ Lsum) {
    __shared__ unsigned short Qlds[32 * 512];       // 32 KB, XOR-swizzled granules
    __shared__ unsigned short Plds[2 * 16 * 512];   // 32 KB, 2-slot ring
    __shared__ int prod_done[2], cons_done[2];
    const int tid = threadIdx.x;
    const int s = blockIdx.x & (NSPLIT - 1), qt = blockIdx.x >> 4;
    const int q0 = qt * 32;
    const int wg = tid >> 6, lane = tid & 63, lm = lane & 15, lg = lane >> 4;

    if (tid < 2) { prod_done[tid] = 0; cons_done[tid] = 0; }
    {   // stage Q tile (32x512 bf16), granule-swizzled: g' = g ^ (q&7)
        const uint4* src = (const uint4*)(kwn + q0 * 512);
        #pragma unroll
        for (int i = 0; i < 4; ++i) {
            const int L = (i * 512 + tid) * 8;
            const int q = L >> 9, g = (L & 511) >> 3;
            *(uint4*)&Qlds[q * 512 + ((g ^ (q & 7)) << 3)] = src[i * 512 + tid];
        }
    }
    __syncthreads();   // covers Q staging + flag init

    const f32x4 zero4 = {0.f, 0.f, 0.f, 0.f};
    const int c0 = (s * NCH) / NSPLIT, c1 = ((s + 1) * NCH) / NSPLIT;
    const int n = c1 - c0;

    if (wg < 4) {
        // ================= producer =================
        float lacc[2][4] = {{0.f,0.f,0.f,0.f},{0.f,0.f,0.f,0.f}};
        for (int i = 0; i < n; ++i) {
            const int c = c0 + i;
            const int slot = i & 1, use = i >> 1;
            // ---- S compute (flag-independent: E reads + MFMA only) ----
            f32x4 sacc[2][4];
            #pragma unroll
            for (int a = 0; a < 2; ++a)
                #pragma unroll
                for (int bq = 0; bq < 4; ++bq) sacc[a][bq] = zero4;
            const bf16* Eb = embS + ((size_t)(c * 16 + wg * 4) * 16) * 512 + lane * 8;
            #pragma unroll
            for (int nb = 0; nb < 4; ++nb) {
                bf16x8 bufr[16];                     // 16 KB in flight per batch
                #pragma unroll
                for (int kf = 0; kf < 16; ++kf)
                    bufr[kf] = *(const bf16x8*)(Eb + (nb * 16 + kf) * 512);
                #pragma unroll
                for (int kf = 0; kf < 16; ++kf) {
                    const int ga = kf * 4 + lg;
                    const bf16x8 aq0 = *(const bf16x8*)&Qlds[lm * 512 + ((ga ^ (lm & 7)) << 3)];
                    const bf16x8 aq1 = *(const bf16x8*)&Qlds[(16 + lm) * 512 + ((ga ^ ((16 + lm) & 7)) << 3)];
                    sacc[0][nb] = __builtin_amdgcn_mfma_f32_16x16x32_bf16(aq0, bufr[kf], sacc[0][nb], 0, 0, 0);
                    sacc[1][nb] = __builtin_amdgcn_mfma_f32_16x16x32_bf16(aq1, bufr[kf], sacc[1][nb], 0, 0, 0);
                }
                __builtin_amdgcn_sched_barrier(0);   // bound bufr live range per batch
            }
            // ---- wait slot free, then exp + scatter into ring ----
            while (__hip_atomic_load(&cons_done[slot], __ATOMIC_ACQUIRE,
                                     __HIP_MEMORY_SCOPE_WORKGROUP) < 4 * use)
                __builtin_amdgcn_s_sleep(1);
            unsigned short* Pw = Plds + (slot << 13);
            #pragma unroll
            for (int nb = 0; nb < 4; ++nb) {
                const float rsv = rs[c * 256 + wg * 64 + nb * 16 + lm];
                const int kfg = 2 * wg + (nb >> 1);
                const int hi = 2 * (nb & 1) + (lm >> 3);
                const int jj = lm & 7;
                #pragma unroll
                for (int mb = 0; mb < 2; ++mb) {
                    const int fragbase = (mb * 8 + kfg) * 512;
                    #pragma unroll
                    for (int r = 0; r < 4; ++r) {
                        const float pv = __expf(sacc[mb][nb][r] * rsv);
                        const bf16 pb = (bf16)pv;
                        lacc[mb][r] += (float)pb;   // rounded value for consistency
                        const int ldest = (lg * 4 + r) + 16 * hi;
                        Pw[fragbase + ldest * 8 + jj] = __builtin_bit_cast(unsigned short, pb);
                    }
                }
            }
            if (lane == 0)   // ONE increment per wave (release drains LDS writes)
                __hip_atomic_fetch_add(&prod_done[slot], 1, __ATOMIC_RELEASE,
                                       __HIP_MEMORY_SCOPE_WORKGROUP);
        }
        // Lsum: one atomic per (mb,r) at the very end
        #pragma unroll
        for (int mb = 0; mb < 2; ++mb)
            #pragma unroll
            for (int r = 0; r < 4; ++r) {
                float sum = lacc[mb][r];
                sum += __shfl_xor(sum, 1);
                sum += __shfl_xor(sum, 2);
                sum += __shfl_xor(sum, 4);
                sum += __shfl_xor(sum, 8);
                if (lm == 0) atomicAdd(&Lsum[q0 + mb * 16 + lg * 4 + r], sum);
            }
    } else {
        // ================= consumer =================
        const int cw = wg - 4;             // t-slice index
        f32x4 acc[2][8];
        #pragma unroll
        for (int a = 0; a < 2; ++a)
            #pragma unroll
            for (int bq = 0; bq < 8; ++bq) acc[a][bq] = zero4;
        for (int i = 0; i < n; ++i) {
            const int cc = c0 + i;
            const int slot = i & 1, use = i >> 1;
            const bf16* ETb = embT + ((size_t)(cc * 8) * 32 + cw * 8) * 512 + lane * 8;
            // prefetch kf=0 E-batch BEFORE the flag wait (flag-independent)
            bf16x8 et[8];
            #pragma unroll
            for (int nb = 0; nb < 8; ++nb)
                et[nb] = *(const bf16x8*)(ETb + nb * 512);
            while (__hip_atomic_load(&prod_done[slot], __ATOMIC_ACQUIRE,
                                     __HIP_MEMORY_SCOPE_WORKGROUP) < 4 * (use + 1))
                __builtin_amdgcn_s_sleep(1);
            const unsigned short* Pb = Plds + (slot << 13);
            #pragma unroll
            for (int kf = 0; kf < 8; ++kf) {
                const bf16x8 pf0 = *(const bf16x8*)&Pb[kf * 512 + lane * 8];
                const bf16x8 pf1 = *(const bf16x8*)&Pb[(8 + kf) * 512 + lane * 8];
                #pragma unroll
                for (int nb = 0; nb < 8; ++nb) {
                    acc[0][nb] = __builtin_amdgcn_mfma_f32_16x16x32_bf16(pf0, et[nb], acc[0][nb], 0, 0, 0);
                    acc[1][nb] = __builtin_amdgcn_mfma_f32_16x16x32_bf16(pf1, et[nb], acc[1][nb], 0, 0, 0);
                }
                if (kf < 7) {
                    #pragma unroll
                    for (int nb = 0; nb < 8; ++nb)
                        et[nb] = *(const bf16x8*)(ETb + ((kf + 1) * 32 + nb) * 512);
                }
                __builtin_amdgcn_sched_barrier(0);   // keep et single-buffered
            }
            if (lane == 0)   // ONE increment per wave (release drains LDS reads)
                __hip_atomic_fetch_add(&cons_done[slot], 1, __ATOMIC_RELEASE,
                                       __HIP_MEMORY_SCOPE_WORKGROUP);
        }
        // epilogue: combine partials across v-splits
        #pragma unroll
        for (int mb = 0; mb < 2; ++mb)
            #pragma unroll
            for (int nb = 0; nb < 8; ++nb)
                #pragma unroll
                for (int r = 0; r < 4; ++r) {
                    const int q = q0 + mb * 16 + lg * 4 + r;
                    const int t = cw * 128 + nb * 16 + lm;
                    atomicAdd(&Oacc[q * 512 + t], acc[mb][nb][r]);
                }
    }
}

// ---------------- Kernel D: out = Oacc / Lsum --------------------------------
__global__ __launch_bounds__(256) void k_final(const float* __restrict__ Oacc,
        const float* __restrict__ Lsum, float* __restrict__ out) {
    const int i = blockIdx.x * 256 + threadIdx.x;   // float4 index, 131072 total
    const float4 o = ((const float4*)Oacc)[i];
    const float inv = 1.0f / Lsum[i >> 7];          // 128 float4 per row
    float4 r;
    r.x = o.x * inv; r.y = o.y * inv; r.z = o.z * inv; r.w = o.w * inv;
    ((float4*)out)[i] = r;
}

// ---------------- launcher ---------------------------------------------------
// ws layout (bytes) — total 104,535,040 (proven to fit):
//   0        kwn   bf16 [1024*512]          1,048,576
//   1048576  rs    f32  [49408]               197,632
//   1246208  Oacc  f32  [1024*512]          2,097,152   (zeroed each launch)
//   3343360  Lsum  f32  [1024]                   4,096   (zeroed each launch)
//   3347456  embS  bf16 frag-major          50,593,792
//   53941248 embT  bf16 frag-major          50,593,792
extern "C" void kernel_launch(void* const* d_in, const int* in_sizes, int n_in,
                              void* d_out, int out_size, void* d_ws, size_t ws_size,
                              hipStream_t stream) {
    const float* audio = (const float*)d_in[0];
    const float* W     = (const float*)d_in[1];
    const float* bias  = (const float*)d_in[2];
    const float* emb   = (const float*)d_in[3];
    float* out = (float*)d_out;
    char* ws = (char*)d_ws;

    bf16*  kwn  = (bf16*)(ws);
    float* rs   = (float*)(ws + 1048576);
    float* Oacc = (float*)(ws + 1246208);
    float* Lsum = (float*)(ws + 3343360);
    bf16*  embS = (bf16*)(ws + 3347456);
    bf16*  embT = (bf16*)(ws + 53941248);

    hipMemsetAsync(ws + 1246208, 0, 2097152 + 4096, stream);   // Oacc + Lsum
    k_proj<<<256, 256, 0, stream>>>(audio, W, bias, kwn);
    k_prep<<<VDIM / 64, 256, 0, stream>>>(emb, embS, embT, rs);
    k_attn<<<NQT * NSPLIT, 512, 0, stream>>>(kwn, embS, embT, rs, Oacc, Lsum);
    k_final<<<(out_size / 4) / 256, 256, 0, stream>>>(Oacc, Lsum, out);
}

// Round 7
// 408.491 us; speedup vs baseline: 1.9033x; 1.0599x over previous
//
#include <hip/hip_runtime.h>
#include <math.h>

// Problem constants: B=128,N=8 -> M=1024 rows; D=768; T=512; V=49408
#define VDIM    49408
#define NCH     193          // 49408 / 256 v-chunks
#define NSPLIT  16           // V splits; s = blockIdx&15 -> all 16 WGs of split on XCD s%8
#define NQT     16           // 1024 / 64 query tiles

typedef __bf16 bf16;
typedef __bf16 bf16x8 __attribute__((ext_vector_type(8)));
typedef float  f32x4  __attribute__((ext_vector_type(4)));

// ---------------- Kernel A: kw = audio@W + b, row-normalize -> kwn (bf16) ----
__global__ __launch_bounds__(256) void k_proj(const float* __restrict__ audio,
        const float* __restrict__ W, const float* __restrict__ bias,
        bf16* __restrict__ kwn) {
    __shared__ float a_lds[4 * 768];
    __shared__ float kw_lds[4 * 512];
    __shared__ float rn_lds[4];
    const int tid = threadIdx.x;
    const int q0 = blockIdx.x * 4;

    const float4* asrc = (const float4*)(audio + q0 * 768);
    float4* adst = (float4*)a_lds;
    #pragma unroll
    for (int i = 0; i < 3; ++i) adst[i * 256 + tid] = asrc[i * 256 + tid];
    __syncthreads();

    float acc0[4] = {0.f, 0.f, 0.f, 0.f}, acc1[4] = {0.f, 0.f, 0.f, 0.f};
    #pragma unroll 4
    for (int d = 0; d < 768; ++d) {
        const float w0 = W[d * 512 + tid];
        const float w1 = W[d * 512 + 256 + tid];
        #pragma unroll
        for (int q = 0; q < 4; ++q) {
            const float a = a_lds[q * 768 + d];   // broadcast, conflict-free
            acc0[q] = fmaf(a, w0, acc0[q]);
            acc1[q] = fmaf(a, w1, acc1[q]);
        }
    }
    const float b0 = bias[tid], b1 = bias[256 + tid];
    #pragma unroll
    for (int q = 0; q < 4; ++q) {
        kw_lds[q * 512 + tid]       = acc0[q] + b0;
        kw_lds[q * 512 + 256 + tid] = acc1[q] + b1;
    }
    __syncthreads();

    const int w = tid >> 6, lane = tid & 63;
    {   // wave w handles row w
        float ss = 0.f;
        #pragma unroll
        for (int i = 0; i < 8; ++i) { const float x = kw_lds[w * 512 + lane + i * 64]; ss = fmaf(x, x, ss); }
        #pragma unroll
        for (int o = 1; o < 64; o <<= 1) ss += __shfl_xor(ss, o);
        if (lane == 0) rn_lds[w] = 1.0f / fmaxf(sqrtf(ss), 1e-8f);
    }
    __syncthreads();
    #pragma unroll
    for (int i = 0; i < 8; ++i) {
        const int idx = i * 256 + tid;
        const int q = idx >> 9;
        kwn[(q0 + q) * 512 + (idx & 511)] = (bf16)(kw_lds[idx] * rn_lds[q]);
    }
}

// ---------------- Kernel B: one-pass emb prep --------------------------------
__global__ __launch_bounds__(256) void k_prep(const float* __restrict__ emb,
        bf16* __restrict__ embS, bf16* __restrict__ embT, float* __restrict__ rs) {
    __shared__ unsigned short tile[64 * 512];
    __shared__ float pnorm[64 * 2];
    const int tid = threadIdx.x;
    const int b = blockIdx.x;
    const int v0 = b * 64;
    const int lane = tid & 63;
    const int p = (tid >> 6) & 1;          // wave parity within row

    // 1: coalesced load + fp32 norm partials + bf16 convert + swizzled LDS store
    const float4* src = (const float4*)(emb + (size_t)v0 * 512);
    #pragma unroll
    for (int i = 0; i < 32; ++i) {
        const int L = i * 256 + tid;           // float4 index in 64x128
        const int r = L >> 7, c4 = L & 127;    // whole wave shares one row r
        const float4 x = src[L];
        float ss = x.x * x.x + x.y * x.y + x.z * x.z + x.w * x.w;
        #pragma unroll
        for (int o = 1; o < 64; o <<= 1) ss += __shfl_xor(ss, o);
        if (lane == 0) pnorm[r * 2 + p] = ss;
        const int g = c4 >> 1, half = c4 & 1;
        ushort4 u;
        u.x = __builtin_bit_cast(unsigned short, (bf16)x.x);
        u.y = __builtin_bit_cast(unsigned short, (bf16)x.y);
        u.z = __builtin_bit_cast(unsigned short, (bf16)x.z);
        u.w = __builtin_bit_cast(unsigned short, (bf16)x.w);
        *(ushort4*)&tile[r * 512 + (((g ^ (r & 7)) << 3) + half * 4)] = u;
    }
    __syncthreads();
    if (tid < 64) {
        const float ss = pnorm[tid * 2] + pnorm[tid * 2 + 1];
        rs[v0 + tid] = 10.0f / fmaxf(sqrtf(ss), 1e-8f);   // folds 1/TEMP
    }

    // 2: embS frag-major (uint4 LDS reads, fully coalesced global writes)
    #pragma unroll
    for (int i = 0; i < 16; ++i) {
        const int F = i * 256 + tid;           // out granule 0..4095
        const int frag = F >> 6, l = F & 63;
        const int vt = frag >> 4, kf = frag & 15;
        const int lm = l & 15, lg = l >> 4;
        const int r = vt * 16 + lm, g = kf * 4 + lg;
        const uint4 d = *(const uint4*)&tile[r * 512 + ((g ^ (r & 7)) << 3)];
        *(uint4*)((unsigned short*)embS + ((size_t)(b * 4 + vt) * 16 + kf) * 512 + l * 8) = d;
    }
    // 3: embT frag-major (transpose gather from LDS, coalesced writes)
    #pragma unroll
    for (int i = 0; i < 16; ++i) {
        const int F = i * 256 + tid;
        const int frag = F >> 6, l = F & 63;
        const int kvl = frag >> 5, tt = frag & 31;
        const int lm = l & 15, lg = l >> 4;
        const int t = tt * 16 + lm;
        unsigned short e[8];
        #pragma unroll
        for (int j = 0; j < 8; ++j) {
            const int r = kvl * 32 + lg * 8 + j;
            e[j] = tile[r * 512 + ((((t >> 3) ^ (r & 7)) << 3) + (t & 7))];
        }
        uint4 o;
        o.x = (unsigned)e[0] | ((unsigned)e[1] << 16);
        o.y = (unsigned)e[2] | ((unsigned)e[3] << 16);
        o.z = (unsigned)e[4] | ((unsigned)e[5] << 16);
        o.w = (unsigned)e[6] | ((unsigned)e[7] << 16);
        const int kvg = b * 2 + kvl;           // global v/32 index
        *(uint4*)((unsigned short*)embT + ((size_t)kvg * 32 + tt) * 512 + l * 8) = o;
    }
}

// ---------------- Kernel C: M64 producer/consumer fused attention ------------
// 768 threads = 12 waves. Waves 0-3 (producers): S = Qn@En^T (64q x 64v slice,
// K=512) -> exp -> P-frags into 2-slot ring. Waves 4-11 (consumers): O += P@E,
// each a 64-wide t-slice. Wave-granular flag sync (lane-0 guarded, monotonic).
// M_tile=64 halves table L2 traffic vs M32: each split's chunk stream is read
// by 16 WGs (one XCD) instead of 32.
__global__ __launch_bounds__(768, 3) void k_attn(const bf16* __restrict__ kwn,
        const bf16* __restrict__ embS, const bf16* __restrict__ embT,
        const float* __restrict__ rs, float* __restrict__ Oacc,
        float* __restrict__ Lsum) {
    __shared__ unsigned short Qlds[64 * 512];       // 64 KB, XOR-swizzled granules
    __shared__ unsigned short Plds[2 * 16384];      // 64 KB: 2 slots x (64q x 256v)
    __shared__ int prod_done[2], cons_done[2];
    const int tid = threadIdx.x;
    const int s = blockIdx.x & (NSPLIT - 1), qt = blockIdx.x >> 4;
    const int q0 = qt * 64;
    const int wg = tid >> 6, lane = tid & 63, lm = lane & 15, lg = lane >> 4;

    if (tid < 2) { prod_done[tid] = 0; cons_done[tid] = 0; }
    if (tid < 512) {   // stage Q tile (64x512 bf16), granule-swizzled g' = g^(q&7)
        const uint4* src = (const uint4*)(kwn + q0 * 512);
        #pragma unroll
        for (int i = 0; i < 8; ++i) {
            const int L = (i * 512 + tid) * 8;
            const int q = L >> 9, g = (L & 511) >> 3;
            *(uint4*)&Qlds[q * 512 + ((g ^ (q & 7)) << 3)] = src[i * 512 + tid];
        }
    }
    __syncthreads();   // covers Q staging + flag init

    const f32x4 zero4 = {0.f, 0.f, 0.f, 0.f};
    const int c0 = (s * NCH) / NSPLIT, c1 = ((s + 1) * NCH) / NSPLIT;
    const int n = c1 - c0;

    if (wg < 4) {
        // ================= producer: v-slice wg*64, all 64 q =================
        float lacc[4][4];
        #pragma unroll
        for (int mb = 0; mb < 4; ++mb)
            #pragma unroll
            for (int r = 0; r < 4; ++r) lacc[mb][r] = 0.f;
        for (int i = 0; i < n; ++i) {
            const int c = c0 + i;
            const int slot = i & 1, use = i >> 1;
            // ---- S compute (flag-independent), kf-pipelined E dbuf ----
            f32x4 sacc[4][4];
            #pragma unroll
            for (int mb = 0; mb < 4; ++mb)
                #pragma unroll
                for (int nb = 0; nb < 4; ++nb) sacc[mb][nb] = zero4;
            const bf16* Eb = embS + ((size_t)(c * 16 + wg * 4) * 16) * 512 + lane * 8;
            bf16x8 ebA[4], ebB[4];
            #pragma unroll
            for (int nb = 0; nb < 4; ++nb) ebA[nb] = *(const bf16x8*)(Eb + (nb * 16) * 512);
            #pragma unroll
            for (int kf = 0; kf < 16; ++kf) {
                const bf16x8* cur = (kf & 1) ? ebB : ebA;
                bf16x8* nxt = (kf & 1) ? ebA : ebB;
                if (kf < 15) {
                    #pragma unroll
                    for (int nb = 0; nb < 4; ++nb)
                        nxt[nb] = *(const bf16x8*)(Eb + (nb * 16 + kf + 1) * 512);
                }
                const int goff = ((kf * 4 + lg) ^ (lm & 7)) << 3;
                bf16x8 aq[4];
                #pragma unroll
                for (int mb = 0; mb < 4; ++mb)
                    aq[mb] = *(const bf16x8*)&Qlds[(mb * 16 + lm) * 512 + goff];
                #pragma unroll
                for (int nb = 0; nb < 4; ++nb)
                    #pragma unroll
                    for (int mb = 0; mb < 4; ++mb)
                        sacc[mb][nb] = __builtin_amdgcn_mfma_f32_16x16x32_bf16(aq[mb], cur[nb], sacc[mb][nb], 0, 0, 0);
                __builtin_amdgcn_sched_barrier(0);
            }
            // ---- wait slot free (8 consumers), then exp + scatter ----
            while (__hip_atomic_load(&cons_done[slot], __ATOMIC_ACQUIRE,
                                     __HIP_MEMORY_SCOPE_WORKGROUP) < 8 * use)
                __builtin_amdgcn_s_sleep(1);
            unsigned short* Pw = Plds + (slot << 14);
            #pragma unroll
            for (int nb = 0; nb < 4; ++nb) {
                const float rsv = rs[c * 256 + wg * 64 + nb * 16 + lm];
                const int kv = 2 * wg + (nb >> 1);
                const int lA = ((nb & 1) * 2 + (lm >> 3)) * 16;
                const int jj = lm & 7;
                #pragma unroll
                for (int mb = 0; mb < 4; ++mb) {
                    const int fragbase = (mb * 8 + kv) * 512;
                    #pragma unroll
                    for (int r = 0; r < 4; ++r) {
                        const float pv = __expf(sacc[mb][nb][r] * rsv);
                        const bf16 pb = (bf16)pv;
                        lacc[mb][r] += (float)pb;   // rounded value for consistency
                        const int ldest = lA + lg * 4 + r;
                        Pw[fragbase + ldest * 8 + jj] = __builtin_bit_cast(unsigned short, pb);
                    }
                }
            }
            if (lane == 0)   // ONE increment per wave (release drains LDS writes)
                __hip_atomic_fetch_add(&prod_done[slot], 1, __ATOMIC_RELEASE,
                                       __HIP_MEMORY_SCOPE_WORKGROUP);
        }
        // Lsum: partial over this wave's v-slices, one atomic per q at the end
        #pragma unroll
        for (int mb = 0; mb < 4; ++mb)
            #pragma unroll
            for (int r = 0; r < 4; ++r) {
                float sum = lacc[mb][r];
                sum += __shfl_xor(sum, 1);
                sum += __shfl_xor(sum, 2);
                sum += __shfl_xor(sum, 4);
                sum += __shfl_xor(sum, 8);
                if (lm == 0) atomicAdd(&Lsum[q0 + mb * 16 + lg * 4 + r], sum);
            }
    } else {
        // ================= consumer: t-slice (wg-4)*64, all 64 q =============
        const int cw = wg - 4;
        f32x4 acc[4][4];                   // [mb 16q][nt 16t]
        #pragma unroll
        for (int mb = 0; mb < 4; ++mb)
            #pragma unroll
            for (int nt = 0; nt < 4; ++nt) acc[mb][nt] = zero4;
        for (int i = 0; i < n; ++i) {
            const int cc = c0 + i;
            const int slot = i & 1, use = i >> 1;
            const bf16* ETb = embT + ((size_t)cc * 256 + cw * 4) * 512 + lane * 8;
            // prefetch kf=0 E-batch BEFORE the flag wait (flag-independent)
            bf16x8 etA[4], etB[4];
            #pragma unroll
            for (int nt = 0; nt < 4; ++nt) etA[nt] = *(const bf16x8*)(ETb + nt * 512);
            while (__hip_atomic_load(&prod_done[slot], __ATOMIC_ACQUIRE,
                                     __HIP_MEMORY_SCOPE_WORKGROUP) < 4 * (use + 1))
                __builtin_amdgcn_s_sleep(1);
            const unsigned short* Pb = Plds + (slot << 14);
            #pragma unroll
            for (int kf = 0; kf < 8; ++kf) {
                const bf16x8* cur = (kf & 1) ? etB : etA;
                bf16x8* nxt = (kf & 1) ? etA : etB;
                if (kf < 7) {
                    #pragma unroll
                    for (int nt = 0; nt < 4; ++nt)
                        nxt[nt] = *(const bf16x8*)(ETb + ((kf + 1) * 32 + nt) * 512);
                }
                bf16x8 pf[4];
                #pragma unroll
                for (int mb = 0; mb < 4; ++mb)
                    pf[mb] = *(const bf16x8*)&Pb[(mb * 8 + kf) * 512 + lane * 8];
                #pragma unroll
                for (int nt = 0; nt < 4; ++nt)
                    #pragma unroll
                    for (int mb = 0; mb < 4; ++mb)
                        acc[mb][nt] = __builtin_amdgcn_mfma_f32_16x16x32_bf16(pf[mb], cur[nt], acc[mb][nt], 0, 0, 0);
                __builtin_amdgcn_sched_barrier(0);
            }
            if (lane == 0)   // ONE increment per wave (release drains LDS reads)
                __hip_atomic_fetch_add(&cons_done[slot], 1, __ATOMIC_RELEASE,
                                       __HIP_MEMORY_SCOPE_WORKGROUP);
        }
        // epilogue: combine partials across v-splits
        #pragma unroll
        for (int mb = 0; mb < 4; ++mb)
            #pragma unroll
            for (int nt = 0; nt < 4; ++nt)
                #pragma unroll
                for (int r = 0; r < 4; ++r) {
                    const int q = q0 + mb * 16 + lg * 4 + r;
                    const int t = cw * 64 + nt * 16 + lm;
                    atomicAdd(&Oacc[q * 512 + t], acc[mb][nt][r]);
                }
    }
}

// ---------------- Kernel D: out = Oacc / Lsum --------------------------------
__global__ __launch_bounds__(256) void k_final(const float* __restrict__ Oacc,
        const float* __restrict__ Lsum, float* __restrict__ out) {
    const int i = blockIdx.x * 256 + threadIdx.x;   // float4 index, 131072 total
    const float4 o = ((const float4*)Oacc)[i];
    const float inv = 1.0f / Lsum[i >> 7];          // 128 float4 per row
    float4 r;
    r.x = o.x * inv; r.y = o.y * inv; r.z = o.z * inv; r.w = o.w * inv;
    ((float4*)out)[i] = r;
}

// ---------------- launcher ---------------------------------------------------
// ws layout (bytes) — total 104,535,040 (proven to fit):
//   0        kwn   bf16 [1024*512]          1,048,576
//   1048576  rs    f32  [49408]               197,632
//   1246208  Oacc  f32  [1024*512]          2,097,152   (zeroed each launch)
//   3343360  Lsum  f32  [1024]                   4,096   (zeroed each launch)
//   3347456  embS  bf16 frag-major          50,593,792
//   53941248 embT  bf16 frag-major          50,593,792
extern "C" void kernel_launch(void* const* d_in, const int* in_sizes, int n_in,
                              void* d_out, int out_size, void* d_ws, size_t ws_size,
                              hipStream_t stream) {
    const float* audio = (const float*)d_in[0];
    const float* W     = (const float*)d_in[1];
    const float* bias  = (const float*)d_in[2];
    const float* emb   = (const float*)d_in[3];
    float* out = (float*)d_out;
    char* ws = (char*)d_ws;

    bf16*  kwn  = (bf16*)(ws);
    float* rs   = (float*)(ws + 1048576);
    float* Oacc = (float*)(ws + 1246208);
    float* Lsum = (float*)(ws + 3343360);
    bf16*  embS = (bf16*)(ws + 3347456);
    bf16*  embT = (bf16*)(ws + 53941248);

    hipMemsetAsync(ws + 1246208, 0, 2097152 + 4096, stream);   // Oacc + Lsum
    k_proj<<<256, 256, 0, stream>>>(audio, W, bias, kwn);
    k_prep<<<VDIM / 64, 256, 0, stream>>>(emb, embS, embT, rs);
    k_attn<<<NQT * NSPLIT, 768, 0, stream>>>(kwn, embS, embT, rs, Oacc, Lsum);
    k_final<<<(out_size / 4) / 256, 256, 0, stream>>>(Oacc, Lsum, out);
}